// Round 14
// baseline (65.748 us; speedup 1.0000x reference)
//
#include <hip/hip_runtime.h>
#include <math.h>

#define N_PTS 16384
#define WID   128
#define NHID  5
#define PPB   16            // points per block
#define NCH   7             // a, zt', zx', zy', zz', ztt'', zlap''  (lap channels merged)
#define COLS  (PPB*NCH)     // 112
#define KPAD  132           // stride 66 dwords == 2 mod 32 -> conflict-free b128 column reads
#define NBLK  (N_PTS/PPB)   // 1024

typedef __attribute__((ext_vector_type(8))) __bf16 bf16x8;
typedef __attribute__((ext_vector_type(4))) float  f32x4;

__device__ __forceinline__ f32x4 splat4(float x) { return (f32x4){x, x, x, x}; }

__device__ __forceinline__ unsigned short f2bf(float x) {
    unsigned int u = __builtin_bit_cast(unsigned int, x);
    u += 0x7FFFu + ((u >> 16) & 1u);          // RNE (no NaNs in this problem)
    return (unsigned short)(u >> 16);
}
__device__ __forceinline__ float bf2f(unsigned short h) {
    unsigned int u = ((unsigned int)h) << 16;
    return __builtin_bit_cast(float, u);
}
// fallback-path split
__device__ __forceinline__ void split_bf(float x, unsigned short& hi, unsigned short& lo) {
    const unsigned int u = __builtin_bit_cast(unsigned int, x);
    hi = (unsigned short)(u >> 16);
    const float rem = x - __builtin_bit_cast(float, u & 0xFFFF0000u);
    lo = (unsigned short)(__builtin_bit_cast(unsigned int, rem) >> 16);
}
// packed bf16 convert: D[15:0]=bf16(v0), D[31:16]=bf16(v1)  (RNE)
__device__ __forceinline__ unsigned int cvtpk(float v0, float v1) {
    unsigned int r;
    asm("v_cvt_pk_bf16_f32 %0, %1, %2" : "=v"(r) : "v"(v0), "v"(v1));
    return r;
}
// split 4 floats into packed hi pair + packed lo pair (lo = exact residual of RNE hi)
__device__ __forceinline__ void split_pk4(const float v0, const float v1,
                                          const float v2, const float v3,
                                          uint2& ph, uint2& pl) {
    const unsigned int h01 = cvtpk(v0, v1);
    const unsigned int h23 = cvtpk(v2, v3);
    const float f0 = __builtin_bit_cast(float, h01 << 16);
    const float f1 = __builtin_bit_cast(float, h01 & 0xFFFF0000u);
    const float f2 = __builtin_bit_cast(float, h23 << 16);
    const float f3 = __builtin_bit_cast(float, h23 & 0xFFFF0000u);
    ph = make_uint2(h01, h23);
    pl = make_uint2(cvtpk(v0 - f0, v1 - f1), cvtpk(v2 - f2, v3 - f3));
}
// a = tanh(x), g = 1 - a^2 (cancellation-free)
__device__ __forceinline__ void fast_tanh_g(float x, float& a, float& g) {
    x = fminf(fmaxf(x, -40.0f), 40.0f);
    const float e = __builtin_amdgcn_exp2f(2.88539008177793f * x);   // exp(2x)
    const float r = __builtin_amdgcn_rcpf(e + 1.0f);
    a = 1.0f - 2.0f * r;
    g = 4.0f * e * r * r;
}

// ---------------- pack uW_hid into MFMA fragment order (bf16 hi/lo) ----------------
// frag f = (l*4+s)*8 + rtg ; lane v supplies A[row = rtg*16 + (v&15)][k = s*32 + (v>>4)*8 + j]
__global__ __launch_bounds__(64) void pack_w(const float* __restrict__ uWhid,
                                             unsigned short* __restrict__ whi,
                                             unsigned short* __restrict__ wlo)
{
    const int f  = blockIdx.x;            // 0..159
    const int v  = threadIdx.x;           // 0..63
    const int l  = f >> 5;
    const int s  = (f >> 3) & 3;
    const int rt = f & 7;
    const int row = rt*16 + (v & 15);
    const int k0  = s*32 + ((v >> 4) << 3);
    const float* src = uWhid + (l*WID + row)*WID + k0;
    unsigned short h[8], lo[8];
#pragma unroll
    for (int j = 0; j < 8; ++j) {
        const float x = src[j];
        h[j]  = f2bf(x);
        lo[j] = f2bf(x - bf2f(h[j]));
    }
    const int off = f*512 + v*8;
    *reinterpret_cast<ushort4*>(&whi[off])   = make_ushort4(h[0],h[1],h[2],h[3]);
    *reinterpret_cast<ushort4*>(&whi[off+4]) = make_ushort4(h[4],h[5],h[6],h[7]);
    *reinterpret_cast<ushort4*>(&wlo[off])   = make_ushort4(lo[0],lo[1],lo[2],lo[3]);
    *reinterpret_cast<ushort4*>(&wlo[off+4]) = make_ushort4(lo[4],lo[5],lo[6],lo[7]);
}

// ---------------- MFMA residual kernel (7-channel jet, 4 waves, 16 pts, 2 blk/CU) ----
// Wave w = rq in [0,4): rows [rq*32, rq*32+32) as 2 row-tiles, all 16 points.
// act[col][k] col-major in LDS, col = ch*16 + p, bf16 hi/lo.
// Channels: 0=a, 1..4 = g*zdot_i, 5 = a''_tt, 6 = a''_lap (xx+yy+zz merged — linear ops
// commute with the sum, so carrying the Laplacian as ONE channel is exact).
// Jet algebra is written as f32x4 ext-vector ops (rows packed) -> v_pk_*_f32 where
// the compiler supports it; identical semantics otherwise.
__global__ __launch_bounds__(256, 2) void resid_mfma(
    const float* __restrict__ gt, const float* __restrict__ gx,
    const float* __restrict__ gy, const float* __restrict__ gz,
    const float* __restrict__ uWin, const float* __restrict__ ubin,
    const float* __restrict__ ubhid, const float* __restrict__ uWout,
    const unsigned short* __restrict__ whi, const unsigned short* __restrict__ wlo,
    const float* __restrict__ pWin, const float* __restrict__ pbin,
    const float* __restrict__ pWhid, const float* __restrict__ pbhid,
    const float* __restrict__ pWout, const float* __restrict__ pbout,
    float* __restrict__ out)
{
    __shared__ unsigned short act_h[COLS*KPAD];   // 29568 B
    __shared__ unsigned short act_l[COLS*KPAD];   // 29568 B
    __shared__ float pts4[PPB][4];                // 256 B
    __shared__ float psi_h1[PPB][32];             // 2048 B
    __shared__ float c2s[PPB];                    // 64 B
    __shared__ float psum[4][PPB][2];             // 512 B   -> total ~62 KB (2 blocks/CU)

    const int tid  = threadIdx.x;
    const int rq   = tid >> 6;          // wave = row quarter
    const int v    = tid & 63;
    const int base = blockIdx.x * PPB;

    if (tid < PPB) {
        pts4[tid][0] = gt[base+tid]; pts4[tid][1] = gx[base+tid];
        pts4[tid][2] = gy[base+tid]; pts4[tid][3] = gz[base+tid];
    }
    __syncthreads();

    // ---- input layer 4 -> 128 (256 threads: 16 pt x 16 neuron-groups of 8) ----
    {
        const int p  = tid & 15;
        const int gg = tid >> 4;            // 0..15
        const float q0 = pts4[p][0], q1 = pts4[p][1], q2 = pts4[p][2], q3 = pts4[p][3];
#pragma unroll
        for (int c4 = 0; c4 < 2; ++c4) {
            float vf[NCH][4];
#pragma unroll
            for (int i = 0; i < 4; ++i) {
                const int n = gg*8 + c4*4 + i;
                const float4 wr = *reinterpret_cast<const float4*>(&uWin[n*4]);
                const float z = ubin[n] + wr.x*q0 + wr.y*q1 + wr.z*q2 + wr.w*q3;
                float a, g;  fast_tanh_g(z, a, g);
                const float m = -2.0f * a * g;
                vf[0][i] = a;
                vf[1][i] = g*wr.x; vf[2][i] = g*wr.y; vf[3][i] = g*wr.z; vf[4][i] = g*wr.w;
                vf[5][i] = m*wr.x*wr.x;                                   // tt
                vf[6][i] = m*(wr.y*wr.y + wr.z*wr.z + wr.w*wr.w);         // xx+yy+zz
            }
            const int n0 = gg*8 + c4*4;
#pragma unroll
            for (int ch = 0; ch < NCH; ++ch) {
                uint2 ph, pl;
                split_pk4(vf[ch][0], vf[ch][1], vf[ch][2], vf[ch][3], ph, pl);
                const int off = (ch*PPB + p)*KPAD + n0;
                *reinterpret_cast<uint2*>(&act_h[off]) = ph;
                *reinterpret_cast<uint2*>(&act_l[off]) = pl;
            }
        }
    }
    // ---- psi stage 1: h1 = tanh(pW_in . pt + pb_in), 16 threads per point ----
    {
        const int p = tid >> 4, sub = tid & 15;
        const float q0 = pts4[p][0], q1 = pts4[p][1], q2 = pts4[p][2], q3 = pts4[p][3];
#pragma unroll
        for (int rr = 0; rr < 2; ++rr) {
            const int r = sub*2 + rr;
            const float4 wr = *reinterpret_cast<const float4*>(&pWin[r*4]);
            float a, gd;
            fast_tanh_g(pbin[r] + wr.x*q0 + wr.y*q1 + wr.z*q2 + wr.w*q3, a, gd);
            psi_h1[p][r] = a;
        }
    }
    __syncthreads();

    // ---- psi stage 2: c2 = (1 + psi)^2 ----
    {
        const int p = tid >> 4, sub = tid & 15;
        float partial = 0.f;
#pragma unroll
        for (int rr = 0; rr < 2; ++rr) {
            const int r = sub*2 + rr;
            float s = pbhid[r];
#pragma unroll
            for (int j = 0; j < 32; ++j) s = fmaf(pWhid[r*32+j], psi_h1[p][j], s);
            float a, gd;  fast_tanh_g(s, a, gd);
            partial = fmaf(pWout[r], a, partial);
        }
        partial += __shfl_xor(partial, 1);
        partial += __shfl_xor(partial, 2);
        partial += __shfl_xor(partial, 4);
        partial += __shfl_xor(partial, 8);
        if (sub == 0) {
            const float c = 1.0f + pbout[0] + partial;
            c2s[p] = c * c;
        }
    }

    // ---- 5 hidden layers via MFMA ----
    f32x4 acc[2][NCH];
    const int g4    = (v >> 4) << 2;          // D-row base within tile
    const int lrow0 = rq * 32;
    const int bcol  = v & 15;                 // point index
    const int krow  = (v >> 4) << 3;

    for (int l = 0; l < NHID; ++l) {
#pragma unroll
        for (int rt = 0; rt < 2; ++rt) {
            acc[rt][0] = *reinterpret_cast<const f32x4*>(&ubhid[l*WID + lrow0 + rt*16 + g4]);
#pragma unroll
            for (int ct = 1; ct < NCH; ++ct) acc[rt][ct] = (f32x4){0.f,0.f,0.f,0.f};
        }
#pragma unroll
        for (int s = 0; s < 4; ++s) {
            bf16x8 bh[NCH], bl[NCH], ah[2], al[2];
            const int kof = s*32 + krow;
            const int fb  = ((l*4 + s)*8 + rq*2)*512 + v*8;
#pragma unroll
            for (int rt = 0; rt < 2; ++rt) {
                ah[rt] = *reinterpret_cast<const bf16x8*>(&whi[fb + rt*512]);
                al[rt] = *reinterpret_cast<const bf16x8*>(&wlo[fb + rt*512]);
            }
#pragma unroll
            for (int ct = 0; ct < NCH; ++ct) {
                const int off = (ct*PPB + bcol)*KPAD + kof;
                bh[ct] = *reinterpret_cast<const bf16x8*>(&act_h[off]);
                bl[ct] = *reinterpret_cast<const bf16x8*>(&act_l[off]);
            }
            __builtin_amdgcn_s_setprio(1);
            // group 1: Whi x Ahi
#pragma unroll
            for (int rt = 0; rt < 2; ++rt)
#pragma unroll
                for (int ct = 0; ct < NCH; ++ct)
                    acc[rt][ct] = __builtin_amdgcn_mfma_f32_16x16x32_bf16(ah[rt], bh[ct], acc[rt][ct], 0,0,0);
            // group 2: Whi x Alo
#pragma unroll
            for (int rt = 0; rt < 2; ++rt)
#pragma unroll
                for (int ct = 0; ct < NCH; ++ct)
                    acc[rt][ct] = __builtin_amdgcn_mfma_f32_16x16x32_bf16(ah[rt], bl[ct], acc[rt][ct], 0,0,0);
            // group 3: Wlo x Ahi
#pragma unroll
            for (int rt = 0; rt < 2; ++rt)
#pragma unroll
                for (int ct = 0; ct < NCH; ++ct)
                    acc[rt][ct] = __builtin_amdgcn_mfma_f32_16x16x32_bf16(al[rt], bh[ct], acc[rt][ct], 0,0,0);
            __builtin_amdgcn_s_setprio(0);
        }

        if (l < NHID-1) {
            // ---- jet nonlinearity + split, in registers, BEFORE the barrier ----
            // f32x4-vectorized over the 4 rows of each acc fragment.
            const int p = v & 15;
            uint2 ph[2][NCH], pl[2][NCH];
#pragma unroll
            for (int rt = 0; rt < 2; ++rt) {
                const f32x4 z1 = acc[rt][1], z2 = acc[rt][2];
                const f32x4 z3 = acc[rt][3], z4 = acc[rt][4];
                f32x4 aa, ga;
#pragma unroll
                for (int r = 0; r < 4; ++r) {
                    float a, g;  fast_tanh_g(acc[rt][0][r], a, g);
                    aa[r] = a;  ga[r] = g;
                }
                const f32x4 m2a = splat4(-2.0f) * aa;
                f32x4 vf[NCH];
                vf[0] = aa;
                vf[1] = ga * z1;  vf[2] = ga * z2;
                vf[3] = ga * z3;  vf[4] = ga * z4;
                vf[5] = ga * (m2a * (z1 * z1) + acc[rt][5]);
                const f32x4 s2 = z2*z2 + z3*z3 + z4*z4;
                vf[6] = ga * (m2a * s2 + acc[rt][6]);
#pragma unroll
                for (int ch = 0; ch < NCH; ++ch)
                    split_pk4(vf[ch][0], vf[ch][1], vf[ch][2], vf[ch][3], ph[rt][ch], pl[rt][ch]);
            }
            __syncthreads();   // all reads of act done before overwrite
#pragma unroll
            for (int rt = 0; rt < 2; ++rt) {
                const int n0 = lrow0 + rt*16 + g4;
#pragma unroll
                for (int ch = 0; ch < NCH; ++ch) {
                    const int off = (ch*PPB + p)*KPAD + n0;
                    *reinterpret_cast<uint2*>(&act_h[off]) = ph[rt][ch];
                    *reinterpret_cast<uint2*>(&act_l[off]) = pl[rt][ch];
                }
            }
            __syncthreads();
        }
    }

    // ---- output layer: d_tt and lap, jet fused, f32x4-vectorized ----
    f32x4 p0v = splat4(0.f), p1v = splat4(0.f);
#pragma unroll
    for (int rt = 0; rt < 2; ++rt) {
        const f32x4 w4 = *reinterpret_cast<const f32x4*>(&uWout[lrow0 + rt*16 + g4]);
        const f32x4 z1 = acc[rt][1], z2 = acc[rt][2];
        const f32x4 z3 = acc[rt][3], z4 = acc[rt][4];
        f32x4 aa, ga;
#pragma unroll
        for (int r = 0; r < 4; ++r) {
            float a, g;  fast_tanh_g(acc[rt][0][r], a, g);
            aa[r] = a;  ga[r] = g;
        }
        const f32x4 m2a = splat4(-2.0f) * aa;
        const f32x4 corr5 = ga * (m2a * (z1 * z1) + acc[rt][5]);
        const f32x4 s2 = z2*z2 + z3*z3 + z4*z4;
        const f32x4 corr6 = ga * (m2a * s2 + acc[rt][6]);
        p0v = p0v + w4 * corr5;
        p1v = p1v + w4 * corr6;
    }
    float part0 = p0v[0] + p0v[1] + p0v[2] + p0v[3];
    float part1 = p1v[0] + p1v[1] + p1v[2] + p1v[3];
    part0 += __shfl_xor(part0, 16); part0 += __shfl_xor(part0, 32);
    part1 += __shfl_xor(part1, 16); part1 += __shfl_xor(part1, 32);
    if (v < PPB) {
        psum[rq][v][0] = part0; psum[rq][v][1] = part1;
    }
    __syncthreads();
    if (tid < PPB) {
        const float d0  = psum[0][tid][0] + psum[1][tid][0] + psum[2][tid][0] + psum[3][tid][0];
        const float lap = psum[0][tid][1] + psum[1][tid][1] + psum[2][tid][1] + psum[3][tid][1];
        out[base+tid] = d0 - c2s[tid]*lap;
    }
}

// ---------------- fallback path (fp32, verified round 1; 9-channel) ----------------
__global__ __launch_bounds__(64) void psi_kernel(
    const float* __restrict__ gt, const float* __restrict__ gx,
    const float* __restrict__ gy, const float* __restrict__ gz,
    const float* __restrict__ pWin, const float* __restrict__ pbin,
    const float* __restrict__ pWhid, const float* __restrict__ pbhid,
    const float* __restrict__ pWout, const float* __restrict__ pbout,
    float* __restrict__ c2)
{
    const int i = blockIdx.x * 64 + threadIdx.x;
    if (i >= N_PTS) return;
    const float q0 = gt[i], q1 = gx[i], q2 = gy[i], q3 = gz[i];
    float h1[32];
#pragma unroll
    for (int r = 0; r < 32; ++r) {
        float s = pbin[r] + pWin[r*4+0]*q0 + pWin[r*4+1]*q1
                + pWin[r*4+2]*q2 + pWin[r*4+3]*q3;
        h1[r] = tanhf(s);
    }
    float psi = pbout[0];
#pragma unroll 4
    for (int r = 0; r < 32; ++r) {
        float s = pbhid[r];
#pragma unroll
        for (int j = 0; j < 32; ++j) s = fmaf(pWhid[r*32+j], h1[j], s);
        psi = fmaf(pWout[r], tanhf(s), psi);
    }
    const float c = 1.0f + psi;
    c2[i] = c * c;
}

__global__ __launch_bounds__(256, 2) void resid_f32(
    const float* __restrict__ gt, const float* __restrict__ gx,
    const float* __restrict__ gy, const float* __restrict__ gz,
    const float* __restrict__ uWin, const float* __restrict__ ubin,
    const float* __restrict__ uWhid, const float* __restrict__ ubhid,
    const float* __restrict__ uWout,
    const float* __restrict__ c2g, float* __restrict__ out)
{
    __shared__ float act[WID][16*9];
    __shared__ float ptsh[16][4];
    __shared__ float dsh[16][4];
    const int tid  = threadIdx.x;
    const int rg   = tid >> 4;
    const int p    = tid & 15;
    const int base = blockIdx.x * 16;
    const int row0 = rg * 8;
    const int c0   = p * 9;
    if (tid < 16) {
        ptsh[tid][0] = gt[base+tid]; ptsh[tid][1] = gx[base+tid];
        ptsh[tid][2] = gy[base+tid]; ptsh[tid][3] = gz[base+tid];
    }
    __syncthreads();
    {
        const float q0 = ptsh[p][0], q1 = ptsh[p][1], q2 = ptsh[p][2], q3 = ptsh[p][3];
#pragma unroll
        for (int r = 0; r < 8; ++r) {
            const int row = row0 + r;
            const float w0 = uWin[row*4+0], w1 = uWin[row*4+1];
            const float w2 = uWin[row*4+2], w3 = uWin[row*4+3];
            const float zz = ubin[row] + w0*q0 + w1*q1 + w2*q2 + w3*q3;
            const float a  = tanhf(zz);
            const float g  = 1.0f - a*a;
            const float m2 = -2.0f * a * g;
            act[row][c0+0] = a;
            act[row][c0+1] = g*w0; act[row][c0+2] = g*w1;
            act[row][c0+3] = g*w2; act[row][c0+4] = g*w3;
            act[row][c0+5] = m2*w0*w0; act[row][c0+6] = m2*w1*w1;
            act[row][c0+7] = m2*w2*w2; act[row][c0+8] = m2*w3*w3;
        }
    }
    __syncthreads();
    for (int l = 0; l < NHID; ++l) {
        const float* __restrict__ Wl = uWhid + l*WID*WID;
        float accv[8][9];
#pragma unroll
        for (int r = 0; r < 8; ++r) {
            accv[r][0] = ubhid[l*WID + row0 + r];
#pragma unroll
            for (int c = 1; c < 9; ++c) accv[r][c] = 0.0f;
        }
        for (int k0 = 0; k0 < WID; k0 += 4) {
            float4 wv[8];
#pragma unroll
            for (int r = 0; r < 8; ++r)
                wv[r] = *reinterpret_cast<const float4*>(&Wl[(row0+r)*WID + k0]);
            float hv[4][9];
#pragma unroll
            for (int kk = 0; kk < 4; ++kk)
#pragma unroll
                for (int c = 0; c < 9; ++c) hv[kk][c] = act[k0+kk][c0+c];
#pragma unroll
            for (int kk = 0; kk < 4; ++kk)
#pragma unroll
                for (int r = 0; r < 8; ++r) {
                    const float wk = reinterpret_cast<const float*>(&wv[r])[kk];
#pragma unroll
                    for (int c = 0; c < 9; ++c) accv[r][c] = fmaf(wk, hv[kk][c], accv[r][c]);
                }
        }
        __syncthreads();
#pragma unroll
        for (int r = 0; r < 8; ++r) {
            const int row = row0 + r;
            const float a = tanhf(accv[r][0]);
            const float g = 1.0f - a*a;
            act[row][c0+0] = a;
#pragma unroll
            for (int i = 0; i < 4; ++i) {
                const float zd  = accv[r][1+i];
                const float zdd = accv[r][5+i];
                act[row][c0+1+i] = g*zd;
                act[row][c0+5+i] = g*(zdd - 2.0f*a*zd*zd);
            }
        }
        __syncthreads();
    }
    if (tid < 64) {
        const int pp = tid >> 2, ii = tid & 3;
        float s = 0.0f;
        for (int k = 0; k < WID; ++k) s = fmaf(uWout[k], act[k][pp*9+5+ii], s);
        dsh[pp][ii] = s;
    }
    __syncthreads();
    if (tid < 16) {
        const float d0  = dsh[tid][0];
        const float lap = dsh[tid][1] + dsh[tid][2] + dsh[tid][3];
        out[base+tid] = d0 - c2g[base+tid]*lap;
    }
}

extern "C" void kernel_launch(void* const* d_in, const int* in_sizes, int n_in,
                              void* d_out, int out_size, void* d_ws, size_t ws_size,
                              hipStream_t stream)
{
    const float* gt    = (const float*)d_in[0];
    const float* gx    = (const float*)d_in[1];
    const float* gy    = (const float*)d_in[2];
    const float* gz    = (const float*)d_in[3];
    const float* uWin  = (const float*)d_in[4];
    const float* ubin  = (const float*)d_in[5];
    const float* uWhid = (const float*)d_in[6];
    const float* ubhid = (const float*)d_in[7];
    const float* uWout = (const float*)d_in[8];
    const float* pWin  = (const float*)d_in[10];
    const float* pbin  = (const float*)d_in[11];
    const float* pWhid = (const float*)d_in[12];
    const float* pbhid = (const float*)d_in[13];
    const float* pWout = (const float*)d_in[14];
    const float* pbout = (const float*)d_in[15];
    float* out = (float*)d_out;

    if (ws_size >= 327680) {
        unsigned short* whi = (unsigned short*)d_ws;
        unsigned short* wlo = whi + 81920;                       // 160 KB in
        pack_w<<<160, 64, 0, stream>>>(uWhid, whi, wlo);
        resid_mfma<<<NBLK, 256, 0, stream>>>(gt, gx, gy, gz,
                uWin, ubin, ubhid, uWout, whi, wlo,
                pWin, pbin, pWhid, pbhid, pWout, pbout, out);
    } else {
        float* c2 = (float*)d_ws;
        psi_kernel<<<N_PTS/64, 64, 0, stream>>>(gt, gx, gy, gz,
                pWin, pbin, pWhid, pbhid, pWout, pbout, c2);
        resid_f32<<<N_PTS/16, 256, 0, stream>>>(gt, gx, gy, gz,
                uWin, ubin, uWhid, ubhid, uWout, c2, out);
    }
}